// Round 21
// baseline (351.315 us; speedup 1.0000x reference)
//
#include <hip/hip_runtime.h>
#include <hip/hip_bf16.h>
#include <cstdint>

typedef __attribute__((ext_vector_type(8))) short bf16x8;
typedef __attribute__((ext_vector_type(4))) float f32x4;
typedef __attribute__((ext_vector_type(8))) unsigned short u16x8;
typedef __attribute__((ext_vector_type(4))) unsigned int u32x4;

__device__ __forceinline__ unsigned short f2bf(float f) {
    unsigned int u = __float_as_uint(f);
    unsigned int r = (u + 0x7fffu + ((u >> 16) & 1u)) >> 16;
    return (unsigned short)r;
}

__device__ __forceinline__ float tanh_fast(float x) {
    return 1.0f - 2.0f / (__expf(2.0f * x) + 1.0f);
}

#define GLDS(SRC, DST) __builtin_amdgcn_global_load_lds(                         \
        (const __attribute__((address_space(1))) void*)(SRC),                    \
        (__attribute__((address_space(3))) void*)(DST), 16, 0, 0)

// ---------- K0: fused prep: wv_tile (0..255) | qproj (256..383) |
//                loc_le (384..895) | ctx+rowsum zero (896) ----------
__global__ __launch_bounds__(256) void prep_kernel(
        const float* __restrict__ wv, unsigned short* __restrict__ wvT,
        const float* __restrict__ query, const float* __restrict__ w_q,
        float* __restrict__ ws_q,
        const float* __restrict__ pa, const float* __restrict__ conv_w,
        const float* __restrict__ conv_b, const float* __restrict__ w_u,
        float* __restrict__ le, float* __restrict__ ctx_out,
        float* __restrict__ rowsum) {
    __shared__ __align__(16) char smem[16640];
    const int bid = blockIdx.x;
    const int t = threadIdx.x;

    if (bid < 256) {
        // ---- wv -> bf16 fragment-tiled B (per head, BK=32 layout) ----
        float (*tile)[129] = reinterpret_cast<float(*)[129]>(smem);
        const int h = bid >> 5, kt = bid & 31;
        for (int i = t; i < 1024; i += 256) {
            const int fl = i >> 5;
            const int e4 = (i & 31) * 4;
            const float4 v = *reinterpret_cast<const float4*>(
                wv + (size_t)(kt * 32 + fl) * 1024 + h * 128 + e4);
            tile[fl][e4 + 0] = v.x; tile[fl][e4 + 1] = v.y;
            tile[fl][e4 + 2] = v.z; tile[fl][e4 + 3] = v.w;
        }
        __syncthreads();
#pragma unroll
        for (int cc2 = 0; cc2 < 2; ++cc2) {
            const int c = cc2 * 256 + t;
            const int cb = c >> 6, kg = (c >> 4) & 3, ccl = c & 15;
            const int e_local = cb * 16 + ccl;
            u16x8 u;
#pragma unroll
            for (int jj = 0; jj < 8; ++jj) u[jj] = f2bf(tile[kg * 8 + jj][e_local]);
            *reinterpret_cast<u16x8*>(wvT + (((size_t)h * 32 + kt) * 512 + c) * 8) = u;
        }
    } else if (bid < 384) {
        // ---- q projection: one (b,h) per block ----
        float* qs = reinterpret_cast<float*>(smem);
        const int bh = bid - 256;
        const int b = bh >> 3, h = bh & 7;
        for (int i = t; i < 1024; i += 256) qs[i] = query[(size_t)b * 1024 + i];
        __syncthreads();
        if (t < 128) {
            float acc = 0.f;
            const float* wcol = w_q + h * 128 + t;
            for (int f = 0; f < 1024; ++f) acc = fmaf(qs[f], wcol[(size_t)f * 1024], acc);
            ws_q[(size_t)bh * 128 + t] = acc;
        }
    } else if (bid < 896) {
        // ---- fused conv1d + location-energy ----
        float* pas = reinterpret_cast<float*>(smem);            // 8*132
        float* wu_s = pas + 1056;                               // 10*128
        float* cw = wu_s + 1280;                                // 240
        float* cb = cw + 240;                                   // 16
        const int idx = bid - 384;
        const int b = idx >> 5, k0 = (idx & 31) * 128;
        for (int i = t; i < 8 * 130; i += 256) {
            const int hh = i / 130, kk = i % 130;
            const int gk = k0 + kk - 1;
            pas[hh * 132 + kk] = (gk >= 0 && gk < 4096)
                ? pa[((size_t)(b * 8 + hh)) * 4096 + gk] : 0.f;
        }
        for (int i = t; i < 1280; i += 256) wu_s[i] = w_u[i];
        if (t < 240) cw[t] = conv_w[t];
        if (t < 10) cb[t] = conv_b[t];
        __syncthreads();
        const int k = t >> 1;
        const int d0 = (t & 1) * 64;
        float lc[10];
#pragma unroll
        for (int c = 0; c < 10; ++c) {
            float acc = cb[c];
#pragma unroll
            for (int hh = 0; hh < 8; ++hh) {
                acc += pas[hh * 132 + k] * cw[(c * 8 + hh) * 3 + 0]
                     + pas[hh * 132 + k + 1] * cw[(c * 8 + hh) * 3 + 1]
                     + pas[hh * 132 + k + 2] * cw[(c * 8 + hh) * 3 + 2];
            }
            lc[c] = acc;
        }
        float* dst = le + ((size_t)(b * 4096) + k0 + k) * 128 + d0;
#pragma unroll
        for (int dd = 0; dd < 64; dd += 4) {
            float4 o;
#pragma unroll
            for (int jj = 0; jj < 4; ++jj) {
                float s = 0.f;
#pragma unroll
                for (int c = 0; c < 10; ++c) s += lc[c] * wu_s[c * 128 + d0 + dd + jj];
                ((float*)&o)[jj] = tanh_fast(s);
            }
            *reinterpret_cast<float4*>(dst + dd) = o;
        }
    } else {
        // ---- zero context (16384 floats) + rowsum (128 floats) ----
        float4 z = {0.f, 0.f, 0.f, 0.f};
        for (int i = t; i < 4096; i += 256)
            *reinterpret_cast<float4*>(ctx_out + (size_t)i * 4) = z;
        if (t < 128) rowsum[t] = 0.f;
    }
}

// ---------- K3: GEMM + exp-score + fused context GEMV (T14 value prefetch) ----
// BM=128, BN=256 (2 heads), BK=32; 512 thr, 8 waves (2M x 4N), wave 64x64.
// Ring-3 LDS, one barrier/kt. Value rows 0..63 prefetched into regs BEFORE
// epilogue-1 (loads hide under the exp/tanh VALU chain); rows 64..127 loaded
// while the first 32 FMAs execute.
#define NT 32
__global__ __launch_bounds__(512) void gemm_score_kernel(
        const float* __restrict__ key_in, const unsigned short* __restrict__ wvT_tiled,
        const float* __restrict__ le, const float* __restrict__ value,
        const float* __restrict__ ws_q, const float* __restrict__ bias,
        const float* __restrict__ score_w, const float* __restrict__ score_b,
        float* __restrict__ align_out, float* __restrict__ rowsum,
        float* __restrict__ ctx_out) {
    __shared__ __align__(16) unsigned short As[3][4096];    // 24 KB
    __shared__ __align__(16) unsigned short Bs[3][8192];    // 48 KB
    __shared__ float qb_sm[256], sw_sm[128];
    __shared__ float partial[128][4];                       // reused as comb[512]
    __shared__ float e_sm[256];                             // [hh*128 + r]

    const int t = threadIdx.x;
    const int lane = t & 63, wid = t >> 6;
    const int wm = wid >> 2;          // 0..1 : M-half
    const int wn = wid & 3;           // 0..3 : (head, d-half)

    // XCD swizzle: the 4 head-pair blocks of one panel adjacent on one XCD
    const int fid = blockIdx.x;       // 0..2047
    const int x = fid & 7, j = fid >> 3;     // j: 0..255
    const int bm = x * 64 + (j >> 2);        // panel 0..511 (128 rows)
    const int hp = j & 3;                    // head-pair 0..3
    const int b = bm >> 5;
    const int kk0 = (bm & 31) << 7;

    if (t < 256) {
        const int hh = t >> 7, d = t & 127;
        qb_sm[t] = ws_q[(size_t)(b * 8 + hp * 2 + hh) * 128 + d] + bias[d];
        if (t < 128) sw_sm[t] = score_w[t];
    }

    // ---- A staging: thread t reads row r_=t>>2, kseg ks=t&3 (coalesced 128B/4 lanes)
    const int r_ = t >> 2, ks = t & 3;
    const float* aRow = key_in + ((size_t)(b * 4096 + kk0) + r_) * 1024 + ks * 8;
    const int cW = (t >> 6) * 64 + ks * 16 + (r_ & 15);
    const int dst0 = (cW ^ (ks | ((ks & 1) << 2))) * 8;            // ushort idx

    // fragment-read lane swizzle (same involution): kg = lane>>4
    const int kgR = lane >> 4;
    const int laneSwz = lane ^ (kgR | ((kgR & 1) << 2));

    // ---- B staging: thread stages two 16B chunks of one head ----
    const unsigned short* bT = wvT_tiled
        + (size_t)(hp * 2 + (t >> 8)) * 131072 + (t & 255) * 8;
    const int dstB = (t >> 8) * 4096 + (t & 255) * 8;              // ushort idx

    float4 st0, st1;

#define LOADA(KT) {                                                               \
        const float* p_ = aRow + (KT) * 32;                                       \
        st0 = *reinterpret_cast<const float4*>(p_);                               \
        st1 = *reinterpret_cast<const float4*>(p_ + 4); }

#define WRITEA(BUF) {                                                             \
        __hip_bfloat162 h0_ = __float22bfloat162_rn({st0.x, st0.y});              \
        __hip_bfloat162 h1_ = __float22bfloat162_rn({st0.z, st0.w});              \
        __hip_bfloat162 h2_ = __float22bfloat162_rn({st1.x, st1.y});              \
        __hip_bfloat162 h3_ = __float22bfloat162_rn({st1.z, st1.w});              \
        u32x4 u_;                                                                 \
        u_[0] = *reinterpret_cast<unsigned int*>(&h0_);                           \
        u_[1] = *reinterpret_cast<unsigned int*>(&h1_);                           \
        u_[2] = *reinterpret_cast<unsigned int*>(&h2_);                           \
        u_[3] = *reinterpret_cast<unsigned int*>(&h3_);                           \
        *reinterpret_cast<u32x4*>(&As[BUF][dst0]) = u_; }

#define STAGE_B(BUF, KT) {                                                        \
        GLDS(bT + (size_t)(KT) * 4096, &Bs[BUF][dstB]);                           \
        GLDS(bT + (size_t)(KT) * 4096 + 2048, &Bs[BUF][dstB + 2048]); }

    f32x4 acc[4][4] = {};

    // prologue: B(0)->buf0, A(0)->buf0 (regs->LDS), preload A(1)
    LOADA(0);
    STAGE_B(0, 0);
    WRITEA(0);
    LOADA(1);

    for (int kt = 0; kt < NT; ++kt) {
        const int cur = kt % 3;
        const int nxt = (kt + 1) % 3;
        STAGE_B(nxt, (kt + 1) & (NT - 1));   // wraps harmlessly on last iter
        WRITEA(nxt);        // regs A(kt+1); implicit vmcnt also certifies B(kt)
        LOADA((kt + 2) & (NT - 1));
        asm volatile("s_waitcnt lgkmcnt(0)\n\t"
                     "s_barrier" ::: "memory");

        bf16x8 af[4], bg[4];
#pragma unroll
        for (int mf = 0; mf < 4; ++mf)
            af[mf] = *reinterpret_cast<const bf16x8*>(
                &As[cur][((wm * 4 + mf) * 64 + laneSwz) * 8]);
#pragma unroll
        for (int nf = 0; nf < 4; ++nf)
            bg[nf] = *reinterpret_cast<const bf16x8*>(
                &Bs[cur][(wn >> 1) * 4096 + ((wn & 1) * 4 + nf) * 512 + lane * 8]);
        __builtin_amdgcn_s_setprio(1);
#pragma unroll
        for (int mf = 0; mf < 4; ++mf)
#pragma unroll
            for (int nf = 0; nf < 4; ++nf)
                acc[mf][nf] = __builtin_amdgcn_mfma_f32_16x16x32_bf16(
                    af[mf], bg[nf], acc[mf][nf], 0, 0, 0);
        __builtin_amdgcn_s_setprio(0);
        // no end-of-kt barrier: ring-3 re-write distance covers the hazard
    }

    // ---- value prefetch chunk 0 (rows p, p+2, .., p+62): no dep on scores ----
    const int colV = t & 255;
    const int pV = t >> 8;
    const float* vcol = value + ((size_t)(b * 4096 + kk0 + pV)) * 1024
                        + hp * 256 + colV;
    float vv[32];
#pragma unroll
    for (int i = 0; i < 32; ++i)
        vv[i] = vcol[(size_t)(2 * i) * 1024];

    // ---- epilogue 1: score -> exp(score); align write + rowsum atomic ----
    const float K2 = 2.8853900817779268f;
    const float LOG2E = 1.4426950408889634f;
    const float sb = score_b[0];
    const int g = lane >> 4;
    const int l15 = lane & 15;
    float kqb[4], swv[4];
#pragma unroll
    for (int nf = 0; nf < 4; ++nf) {
        const int d128 = (wn & 1) * 64 + nf * 16 + l15;
        kqb[nf] = qb_sm[(wn >> 1) * 128 + d128] * K2;
        swv[nf] = sw_sm[d128];
    }
    const float* leB = le + ((size_t)(b * 4096 + kk0) + wm * 64 + g * 4) * 128
                       + (wn & 1) * 64 + l15;

#pragma unroll
    for (int mf = 0; mf < 4; ++mf) {
        float lv[16];
#pragma unroll
        for (int jj = 0; jj < 4; ++jj)
#pragma unroll
            for (int nf = 0; nf < 4; ++nf)
                lv[jj * 4 + nf] = leB[(size_t)(mf * 16 + jj) * 128 + nf * 16];
#pragma unroll
        for (int jj = 0; jj < 4; ++jj) {
            const int row_l = wm * 64 + mf * 16 + g * 4 + jj;
            float sum = 0.f;
#pragma unroll
            for (int nf = 0; nf < 4; ++nf) {
                const float m = fmaf(K2, lv[jj * 4 + nf], kqb[nf]);
                const float tt = fmaf(K2, acc[mf][nf][jj], m);
                const float y = __builtin_amdgcn_exp2f(tt);
                const float r = fmaf(-2.0f, __builtin_amdgcn_rcpf(y + 1.0f), 1.0f);
                sum = fmaf(r, swv[nf], sum);
            }
            sum += __shfl_xor(sum, 1);
            sum += __shfl_xor(sum, 2);
            sum += __shfl_xor(sum, 4);
            sum += __shfl_xor(sum, 8);
            if (l15 == 0) partial[row_l][wn] = sum;
        }
    }
    __syncthreads();
    if (t < 256) {
        const int r = t >> 1, hh = t & 1;
        const float sc = partial[r][hh * 2] + partial[r][hh * 2 + 1] + sb;
        const float e = __builtin_amdgcn_exp2f(sc * LOG2E);
        align_out[(size_t)(b * 8 + hp * 2 + hh) * 4096 + kk0 + r] = e;  // raw
        e_sm[hh * 128 + r] = e;
        float s = e;
        s += __shfl_xor(s, 2);
        s += __shfl_xor(s, 4);
        s += __shfl_xor(s, 8);
        s += __shfl_xor(s, 16);
        s += __shfl_xor(s, 32);
        if ((lane >> 1) == 0)
            atomicAdd(&rowsum[b * 8 + hp * 2 + hh], s);
    }
    __syncthreads();

    // ---- epilogue 2: ctx GEMV; chunk-1 loads in flight under chunk-0 FMAs ----
    {
        const float* es = &e_sm[(colV >> 7) * 128 + pV];
        float vv2[32];
#pragma unroll
        for (int i = 0; i < 32; ++i)
            vv2[i] = vcol[(size_t)(2 * i + 64) * 1024];
        float acc2 = 0.f;
#pragma unroll
        for (int i = 0; i < 32; ++i)
            acc2 = fmaf(es[2 * i], vv[i], acc2);
#pragma unroll
        for (int i = 0; i < 32; ++i)
            acc2 = fmaf(es[2 * i + 64], vv2[i], acc2);
        float* comb = &partial[0][0];
        comb[t] = acc2;
        __syncthreads();
        if (t < 256) {
            const float tot = comb[t] + comb[t + 256];
            atomicAdd(&ctx_out[(size_t)(b * 8 + hp * 2 + (colV >> 7)) * 128
                               + (colV & 127)], tot);
        }
    }
}

// ---------- K4: finalize: align /= rowsum ; ctx /= rowsum ----------
__global__ __launch_bounds__(256) void finalize_kernel(
        float* __restrict__ align_o, float* __restrict__ ctx_out,
        const float* __restrict__ rowsum) {
    const int bid = blockIdx.x;
    const int t = threadIdx.x;
    if (bid < 512) {
        const int bh = bid >> 2;
        const float inv = 1.0f / rowsum[bh];
        float4* p = reinterpret_cast<float4*>(align_o + (size_t)bid * 1024);
        float4 v = p[t];
        v.x *= inv; v.y *= inv; v.z *= inv; v.w *= inv;
        p[t] = v;
    } else {
        const int i = (bid - 512) * 256 + t;   // 64 blocks x 256 = 16384
        ctx_out[i] *= 1.0f / rowsum[i >> 7];
    }
}

extern "C" void kernel_launch(void* const* d_in, const int* in_sizes, int n_in,
                              void* d_out, int out_size, void* d_ws, size_t ws_size,
                              hipStream_t stream) {
    const float* query   = (const float*)d_in[0];
    const float* key_in  = (const float*)d_in[1];
    const float* value   = (const float*)d_in[2];
    const float* pa      = (const float*)d_in[3];
    const float* conv_w  = (const float*)d_in[4];
    const float* conv_b  = (const float*)d_in[5];
    const float* w_u     = (const float*)d_in[6];
    const float* w_q     = (const float*)d_in[7];
    const float* w_v     = (const float*)d_in[8];
    const float* bias    = (const float*)d_in[9];
    const float* score_w = (const float*)d_in[10];
    const float* score_b = (const float*)d_in[11];

    float* out = (float*)d_out;
    float* ctx_out = out;                 // [128,128]
    float* align_out = out + 16384;       // [16,8,4096]

    char* ws = (char*)d_ws;
    const size_t OFF_Q    = 0;                        // 64 KB
    const size_t OFF_RS   = 65536;                    // 512 B (rowsum)
    const size_t OFF_WVT  = 66048;                    // 2 MB (tiled bf16)
    const size_t OFF_LE   = OFF_WVT + 2097152;        // 33.55 MB

    float* ws_q            = (float*)(ws + OFF_Q);
    float* ws_rs           = (float*)(ws + OFF_RS);
    unsigned short* ws_wvT = (unsigned short*)(ws + OFF_WVT);
    float* ws_le           = (float*)(ws + OFF_LE);

    hipLaunchKernelGGL(prep_kernel, dim3(897), dim3(256), 0, stream,
                       w_v, ws_wvT, query, w_q, ws_q,
                       pa, conv_w, conv_b, w_u, ws_le, ctx_out, ws_rs);
    hipLaunchKernelGGL(gemm_score_kernel, dim3(2048), dim3(512), 0, stream,
                       key_in, ws_wvT, ws_le, value, ws_q, bias, score_w, score_b,
                       align_out, ws_rs, ctx_out);
    hipLaunchKernelGGL(finalize_kernel, dim3(576), dim3(256), 0, stream,
                       align_out, ctx_out, ws_rs);
}

// Round 22
// 272.681 us; speedup vs baseline: 1.2884x; 1.2884x over previous
//
#include <hip/hip_runtime.h>
#include <hip/hip_bf16.h>
#include <cstdint>

typedef __attribute__((ext_vector_type(8))) short bf16x8;
typedef __attribute__((ext_vector_type(4))) float f32x4;
typedef __attribute__((ext_vector_type(8))) unsigned short u16x8;
typedef __attribute__((ext_vector_type(4))) unsigned int u32x4;

__device__ __forceinline__ unsigned short f2bf(float f) {
    unsigned int u = __float_as_uint(f);
    unsigned int r = (u + 0x7fffu + ((u >> 16) & 1u)) >> 16;
    return (unsigned short)r;
}

__device__ __forceinline__ float tanh_fast(float x) {
    return 1.0f - 2.0f / (__expf(2.0f * x) + 1.0f);
}

#define GLDS(SRC, DST) __builtin_amdgcn_global_load_lds(                         \
        (const __attribute__((address_space(1))) void*)(SRC),                    \
        (__attribute__((address_space(3))) void*)(DST), 16, 0, 0)

// ---------- K0: fused prep: wv_tile (0..255) | qproj (256..383) |
//                loc_le (384..895) | ctx+rowsum zero (896) ----------
__global__ __launch_bounds__(256) void prep_kernel(
        const float* __restrict__ wv, unsigned short* __restrict__ wvT,
        const float* __restrict__ query, const float* __restrict__ w_q,
        float* __restrict__ ws_q,
        const float* __restrict__ pa, const float* __restrict__ conv_w,
        const float* __restrict__ conv_b, const float* __restrict__ w_u,
        float* __restrict__ le, float* __restrict__ ctx_out,
        float* __restrict__ rowsum) {
    __shared__ __align__(16) char smem[16640];
    const int bid = blockIdx.x;
    const int t = threadIdx.x;

    if (bid < 256) {
        // ---- wv -> bf16 fragment-tiled B (per head, BK=32 layout) ----
        float (*tile)[129] = reinterpret_cast<float(*)[129]>(smem);
        const int h = bid >> 5, kt = bid & 31;
        for (int i = t; i < 1024; i += 256) {
            const int fl = i >> 5;
            const int e4 = (i & 31) * 4;
            const float4 v = *reinterpret_cast<const float4*>(
                wv + (size_t)(kt * 32 + fl) * 1024 + h * 128 + e4);
            tile[fl][e4 + 0] = v.x; tile[fl][e4 + 1] = v.y;
            tile[fl][e4 + 2] = v.z; tile[fl][e4 + 3] = v.w;
        }
        __syncthreads();
#pragma unroll
        for (int cc2 = 0; cc2 < 2; ++cc2) {
            const int c = cc2 * 256 + t;
            const int cb = c >> 6, kg = (c >> 4) & 3, ccl = c & 15;
            const int e_local = cb * 16 + ccl;
            u16x8 u;
#pragma unroll
            for (int jj = 0; jj < 8; ++jj) u[jj] = f2bf(tile[kg * 8 + jj][e_local]);
            *reinterpret_cast<u16x8*>(wvT + (((size_t)h * 32 + kt) * 512 + c) * 8) = u;
        }
    } else if (bid < 384) {
        // ---- q projection: one (b,h) per block ----
        float* qs = reinterpret_cast<float*>(smem);
        const int bh = bid - 256;
        const int b = bh >> 3, h = bh & 7;
        for (int i = t; i < 1024; i += 256) qs[i] = query[(size_t)b * 1024 + i];
        __syncthreads();
        if (t < 128) {
            float acc = 0.f;
            const float* wcol = w_q + h * 128 + t;
            for (int f = 0; f < 1024; ++f) acc = fmaf(qs[f], wcol[(size_t)f * 1024], acc);
            ws_q[(size_t)bh * 128 + t] = acc;
        }
    } else if (bid < 896) {
        // ---- fused conv1d + location-energy ----
        float* pas = reinterpret_cast<float*>(smem);            // 8*132
        float* wu_s = pas + 1056;                               // 10*128
        float* cw = wu_s + 1280;                                // 240
        float* cb = cw + 240;                                   // 16
        const int idx = bid - 384;
        const int b = idx >> 5, k0 = (idx & 31) * 128;
        for (int i = t; i < 8 * 130; i += 256) {
            const int hh = i / 130, kk = i % 130;
            const int gk = k0 + kk - 1;
            pas[hh * 132 + kk] = (gk >= 0 && gk < 4096)
                ? pa[((size_t)(b * 8 + hh)) * 4096 + gk] : 0.f;
        }
        for (int i = t; i < 1280; i += 256) wu_s[i] = w_u[i];
        if (t < 240) cw[t] = conv_w[t];
        if (t < 10) cb[t] = conv_b[t];
        __syncthreads();
        const int k = t >> 1;
        const int d0 = (t & 1) * 64;
        float lc[10];
#pragma unroll
        for (int c = 0; c < 10; ++c) {
            float acc = cb[c];
#pragma unroll
            for (int hh = 0; hh < 8; ++hh) {
                acc += pas[hh * 132 + k] * cw[(c * 8 + hh) * 3 + 0]
                     + pas[hh * 132 + k + 1] * cw[(c * 8 + hh) * 3 + 1]
                     + pas[hh * 132 + k + 2] * cw[(c * 8 + hh) * 3 + 2];
            }
            lc[c] = acc;
        }
        float* dst = le + ((size_t)(b * 4096) + k0 + k) * 128 + d0;
#pragma unroll
        for (int dd = 0; dd < 64; dd += 4) {
            float4 o;
#pragma unroll
            for (int jj = 0; jj < 4; ++jj) {
                float s = 0.f;
#pragma unroll
                for (int c = 0; c < 10; ++c) s += lc[c] * wu_s[c * 128 + d0 + dd + jj];
                ((float*)&o)[jj] = tanh_fast(s);
            }
            *reinterpret_cast<float4*>(dst + dd) = o;
        }
    } else {
        // ---- zero context (16384 floats) + rowsum (128 floats) ----
        float4 z = {0.f, 0.f, 0.f, 0.f};
        for (int i = t; i < 4096; i += 256)
            *reinterpret_cast<float4*>(ctx_out + (size_t)i * 4) = z;
        if (t < 128) rowsum[t] = 0.f;
    }
}

// ---------- K3: GEMM + exp-score + fused context GEMV ----------
// BM=128, BN=256 (2 heads), BK=32; 512 thr, 8 waves (2M x 4N), wave 64x64.
// Ring-3 LDS, one barrier/kt. Epilogue: writes raw exp(score) to align,
// atomic rowsum, then dots exp-scores with value slice (128KB, coalesced)
// and atomic-accumulates UNNORMALIZED context. finalize_kernel divides.
#define NT 32
__global__ __launch_bounds__(512) void gemm_score_kernel(
        const float* __restrict__ key_in, const unsigned short* __restrict__ wvT_tiled,
        const float* __restrict__ le, const float* __restrict__ value,
        const float* __restrict__ ws_q, const float* __restrict__ bias,
        const float* __restrict__ score_w, const float* __restrict__ score_b,
        float* __restrict__ align_out, float* __restrict__ rowsum,
        float* __restrict__ ctx_out) {
    __shared__ __align__(16) unsigned short As[3][4096];    // 24 KB
    __shared__ __align__(16) unsigned short Bs[3][8192];    // 48 KB
    __shared__ float qb_sm[256], sw_sm[128];
    __shared__ float partial[128][4];                       // reused as comb[512]
    __shared__ float e_sm[256];                             // [hh*128 + r]

    const int t = threadIdx.x;
    const int lane = t & 63, wid = t >> 6;
    const int wm = wid >> 2;          // 0..1 : M-half
    const int wn = wid & 3;           // 0..3 : (head, d-half)

    // XCD swizzle: the 4 head-pair blocks of one panel adjacent on one XCD
    const int fid = blockIdx.x;       // 0..2047
    const int x = fid & 7, j = fid >> 3;     // j: 0..255
    const int bm = x * 64 + (j >> 2);        // panel 0..511 (128 rows)
    const int hp = j & 3;                    // head-pair 0..3
    const int b = bm >> 5;
    const int kk0 = (bm & 31) << 7;

    if (t < 256) {
        const int hh = t >> 7, d = t & 127;
        qb_sm[t] = ws_q[(size_t)(b * 8 + hp * 2 + hh) * 128 + d] + bias[d];
        if (t < 128) sw_sm[t] = score_w[t];
    }

    // ---- A staging: thread t reads row r_=t>>2, kseg ks=t&3 (coalesced 128B/4 lanes)
    const int r_ = t >> 2, ks = t & 3;
    const float* aRow = key_in + ((size_t)(b * 4096 + kk0) + r_) * 1024 + ks * 8;
    const int cW = (t >> 6) * 64 + ks * 16 + (r_ & 15);
    const int dst0 = (cW ^ (ks | ((ks & 1) << 2))) * 8;            // ushort idx

    // fragment-read lane swizzle (same involution): kg = lane>>4
    const int kgR = lane >> 4;
    const int laneSwz = lane ^ (kgR | ((kgR & 1) << 2));

    // ---- B staging: thread stages two 16B chunks of one head ----
    const unsigned short* bT = wvT_tiled
        + (size_t)(hp * 2 + (t >> 8)) * 131072 + (t & 255) * 8;
    const int dstB = (t >> 8) * 4096 + (t & 255) * 8;              // ushort idx

    float4 st0, st1;

#define LOADA(KT) {                                                               \
        const float* p_ = aRow + (KT) * 32;                                       \
        st0 = *reinterpret_cast<const float4*>(p_);                               \
        st1 = *reinterpret_cast<const float4*>(p_ + 4); }

#define WRITEA(BUF) {                                                             \
        __hip_bfloat162 h0_ = __float22bfloat162_rn({st0.x, st0.y});              \
        __hip_bfloat162 h1_ = __float22bfloat162_rn({st0.z, st0.w});              \
        __hip_bfloat162 h2_ = __float22bfloat162_rn({st1.x, st1.y});              \
        __hip_bfloat162 h3_ = __float22bfloat162_rn({st1.z, st1.w});              \
        u32x4 u_;                                                                 \
        u_[0] = *reinterpret_cast<unsigned int*>(&h0_);                           \
        u_[1] = *reinterpret_cast<unsigned int*>(&h1_);                           \
        u_[2] = *reinterpret_cast<unsigned int*>(&h2_);                           \
        u_[3] = *reinterpret_cast<unsigned int*>(&h3_);                           \
        *reinterpret_cast<u32x4*>(&As[BUF][dst0]) = u_; }

#define STAGE_B(BUF, KT) {                                                        \
        GLDS(bT + (size_t)(KT) * 4096, &Bs[BUF][dstB]);                           \
        GLDS(bT + (size_t)(KT) * 4096 + 2048, &Bs[BUF][dstB + 2048]); }

    f32x4 acc[4][4] = {};

    // prologue: B(0)->buf0, A(0)->buf0 (regs->LDS), preload A(1)
    LOADA(0);
    STAGE_B(0, 0);
    WRITEA(0);
    LOADA(1);

    for (int kt = 0; kt < NT; ++kt) {
        const int cur = kt % 3;
        const int nxt = (kt + 1) % 3;
        STAGE_B(nxt, (kt + 1) & (NT - 1));   // wraps harmlessly on last iter
        WRITEA(nxt);        // regs A(kt+1); implicit vmcnt also certifies B(kt)
        LOADA((kt + 2) & (NT - 1));
        asm volatile("s_waitcnt lgkmcnt(0)\n\t"
                     "s_barrier" ::: "memory");

        bf16x8 af[4], bg[4];
#pragma unroll
        for (int mf = 0; mf < 4; ++mf)
            af[mf] = *reinterpret_cast<const bf16x8*>(
                &As[cur][((wm * 4 + mf) * 64 + laneSwz) * 8]);
#pragma unroll
        for (int nf = 0; nf < 4; ++nf)
            bg[nf] = *reinterpret_cast<const bf16x8*>(
                &Bs[cur][(wn >> 1) * 4096 + ((wn & 1) * 4 + nf) * 512 + lane * 8]);
        __builtin_amdgcn_s_setprio(1);
#pragma unroll
        for (int mf = 0; mf < 4; ++mf)
#pragma unroll
            for (int nf = 0; nf < 4; ++nf)
                acc[mf][nf] = __builtin_amdgcn_mfma_f32_16x16x32_bf16(
                    af[mf], bg[nf], acc[mf][nf], 0, 0, 0);
        __builtin_amdgcn_s_setprio(0);
        // no end-of-kt barrier: ring-3 re-write distance covers the hazard
    }

    // ---- epilogue 1: score -> exp(score); align write + rowsum atomic ----
    const float K2 = 2.8853900817779268f;
    const float LOG2E = 1.4426950408889634f;
    const float sb = score_b[0];
    const int g = lane >> 4;
    const int l15 = lane & 15;
    float kqb[4], swv[4];
#pragma unroll
    for (int nf = 0; nf < 4; ++nf) {
        const int d128 = (wn & 1) * 64 + nf * 16 + l15;
        kqb[nf] = qb_sm[(wn >> 1) * 128 + d128] * K2;
        swv[nf] = sw_sm[d128];
    }
    const float* leB = le + ((size_t)(b * 4096 + kk0) + wm * 64 + g * 4) * 128
                       + (wn & 1) * 64 + l15;

#pragma unroll
    for (int mf = 0; mf < 4; ++mf) {
        float lv[16];
#pragma unroll
        for (int jj = 0; jj < 4; ++jj)
#pragma unroll
            for (int nf = 0; nf < 4; ++nf)
                lv[jj * 4 + nf] = leB[(size_t)(mf * 16 + jj) * 128 + nf * 16];
#pragma unroll
        for (int jj = 0; jj < 4; ++jj) {
            const int row_l = wm * 64 + mf * 16 + g * 4 + jj;
            float sum = 0.f;
#pragma unroll
            for (int nf = 0; nf < 4; ++nf) {
                const float m = fmaf(K2, lv[jj * 4 + nf], kqb[nf]);
                const float tt = fmaf(K2, acc[mf][nf][jj], m);
                const float y = __builtin_amdgcn_exp2f(tt);
                const float r = fmaf(-2.0f, __builtin_amdgcn_rcpf(y + 1.0f), 1.0f);
                sum = fmaf(r, swv[nf], sum);
            }
            sum += __shfl_xor(sum, 1);
            sum += __shfl_xor(sum, 2);
            sum += __shfl_xor(sum, 4);
            sum += __shfl_xor(sum, 8);
            if (l15 == 0) partial[row_l][wn] = sum;
        }
    }
    __syncthreads();
    if (t < 256) {
        const int r = t >> 1, hh = t & 1;
        const float sc = partial[r][hh * 2] + partial[r][hh * 2 + 1] + sb;
        const float e = __builtin_amdgcn_exp2f(sc * LOG2E);
        align_out[(size_t)(b * 8 + hp * 2 + hh) * 4096 + kk0 + r] = e;  // raw
        e_sm[hh * 128 + r] = e;
        float s = e;
        s += __shfl_xor(s, 2);
        s += __shfl_xor(s, 4);
        s += __shfl_xor(s, 8);
        s += __shfl_xor(s, 16);
        s += __shfl_xor(s, 32);
        if ((lane >> 1) == 0)
            atomicAdd(&rowsum[b * 8 + hp * 2 + hh], s);
    }
    __syncthreads();

    // ---- epilogue 2: context GEMV: ctx[hh,d] += sum_r e[r] * value[r, col] ----
    {
        const int col = t & 255;       // 0..255 across both heads of the pair
        const int p = t >> 8;          // row parity
        const float* vcol = value + ((size_t)(b * 4096 + kk0 + p)) * 1024
                            + hp * 256 + col;
        const float* es = &e_sm[(col >> 7) * 128 + p];
        float acc2 = 0.f;
#pragma unroll 8
        for (int i = 0; i < 64; ++i)
            acc2 = fmaf(es[2 * i], vcol[(size_t)(2 * i) * 1024], acc2);
        float* comb = &partial[0][0];
        comb[t] = acc2;
        __syncthreads();
        if (t < 256) {
            const float tot = comb[t] + comb[t + 256];
            atomicAdd(&ctx_out[(size_t)(b * 8 + hp * 2 + (col >> 7)) * 128
                               + (col & 127)], tot);
        }
    }
}

// ---------- K4: finalize: align /= rowsum ; ctx /= rowsum ----------
__global__ __launch_bounds__(256) void finalize_kernel(
        float* __restrict__ align_o, float* __restrict__ ctx_out,
        const float* __restrict__ rowsum) {
    const int bid = blockIdx.x;
    const int t = threadIdx.x;
    if (bid < 512) {
        const int bh = bid >> 2;
        const float inv = 1.0f / rowsum[bh];
        float4* p = reinterpret_cast<float4*>(align_o + (size_t)bid * 1024);
        float4 v = p[t];
        v.x *= inv; v.y *= inv; v.z *= inv; v.w *= inv;
        p[t] = v;
    } else {
        const int i = (bid - 512) * 256 + t;   // 64 blocks x 256 = 16384
        ctx_out[i] *= 1.0f / rowsum[i >> 7];
    }
}

extern "C" void kernel_launch(void* const* d_in, const int* in_sizes, int n_in,
                              void* d_out, int out_size, void* d_ws, size_t ws_size,
                              hipStream_t stream) {
    const float* query   = (const float*)d_in[0];
    const float* key_in  = (const float*)d_in[1];
    const float* value   = (const float*)d_in[2];
    const float* pa      = (const float*)d_in[3];
    const float* conv_w  = (const float*)d_in[4];
    const float* conv_b  = (const float*)d_in[5];
    const float* w_u     = (const float*)d_in[6];
    const float* w_q     = (const float*)d_in[7];
    const float* w_v     = (const float*)d_in[8];
    const float* bias    = (const float*)d_in[9];
    const float* score_w = (const float*)d_in[10];
    const float* score_b = (const float*)d_in[11];

    float* out = (float*)d_out;
    float* ctx_out = out;                 // [128,128]
    float* align_out = out + 16384;       // [16,8,4096]

    char* ws = (char*)d_ws;
    const size_t OFF_Q    = 0;                        // 64 KB
    const size_t OFF_RS   = 65536;                    // 512 B (rowsum)
    const size_t OFF_WVT  = 66048;                    // 2 MB (tiled bf16)
    const size_t OFF_LE   = OFF_WVT + 2097152;        // 33.55 MB

    float* ws_q            = (float*)(ws + OFF_Q);
    float* ws_rs           = (float*)(ws + OFF_RS);
    unsigned short* ws_wvT = (unsigned short*)(ws + OFF_WVT);
    float* ws_le           = (float*)(ws + OFF_LE);

    hipLaunchKernelGGL(prep_kernel, dim3(897), dim3(256), 0, stream,
                       w_v, ws_wvT, query, w_q, ws_q,
                       pa, conv_w, conv_b, w_u, ws_le, ctx_out, ws_rs);
    hipLaunchKernelGGL(gemm_score_kernel, dim3(2048), dim3(512), 0, stream,
                       key_in, ws_wvT, ws_le, value, ws_q, bias, score_w, score_b,
                       align_out, ws_rs, ctx_out);
    hipLaunchKernelGGL(finalize_kernel, dim3(576), dim3(256), 0, stream,
                       align_out, ctx_out, ws_rs);
}